// Round 11
// baseline (452.011 us; speedup 1.0000x reference)
//
#include <hip/hip_runtime.h>
#include <hip/hip_bf16.h>
#include <cstdint>
#include <cstddef>

#define DEVFN static __device__ __forceinline__

typedef __attribute__((ext_vector_type(8))) short bf16x8;
typedef __attribute__((ext_vector_type(4))) float f32x4;

#define WAITVM(N) asm volatile("s_waitcnt vmcnt(" #N ")" ::: "memory")
#define WAITLGKM() asm volatile("s_waitcnt lgkmcnt(0)" ::: "memory")
#define BAR() __builtin_amdgcn_s_barrier()

DEVFN float exp2f_fast(float x) { return __builtin_amdgcn_exp2f(x); }

DEVFN ushort f2bf(float f) {
  uint32_t u = __float_as_uint(f);
  return (ushort)((u + 0x7fffu + ((u >> 16) & 1u)) >> 16);
}
DEVFN float bf2f(ushort u) { return __uint_as_float((uint32_t)u << 16); }

DEVFN void gl_lds16(const void* g, void* l) {
  __builtin_amdgcn_global_load_lds(
      (const __attribute__((address_space(1))) void*)g,
      (__attribute__((address_space(3))) void*)l, 16, 0, 0);
}

DEVFN float wred_sum(float v) {
#pragma unroll
  for (int o = 32; o; o >>= 1) v += __shfl_xor(v, o);
  return v;
}

// ---------------- fused prep: pack x + all 4 weight transposes ----------------

DEVFN void wtrans_body(const float* __restrict__ in, ushort* __restrict__ out,
                       int K, int N, int bx, int by, int tid, float* tile /*32*33*/) {
  int n0 = bx * 32, k0 = by * 32;
#pragma unroll
  for (int i = 0; i < 4; ++i) {
    int idx = tid + i * 256;
    int r = idx >> 5, c = idx & 31;
    tile[r * 33 + c] = in[(size_t)(k0 + r) * N + n0 + c];
  }
  __syncthreads();
#pragma unroll
  for (int i = 0; i < 4; ++i) {
    int idx = tid + i * 256;
    int r = idx >> 5, c = idx & 31;
    out[(size_t)(n0 + r) * K + k0 + c] = f2bf(tile[c * 33 + r]);
  }
}

__global__ __launch_bounds__(256)
void prep(const float* __restrict__ x, ushort* __restrict__ x_bf,
          const float* __restrict__ w_qkv, ushort* __restrict__ wqkvT,
          const float* __restrict__ w1, ushort* __restrict__ w1T,
          const float* __restrict__ w2, ushort* __restrict__ w2T,
          const float* __restrict__ w_out, ushort* __restrict__ woutT) {
  __shared__ float tile[32 * 33];
  const int blk = blockIdx.x;
  const int tid = threadIdx.x;
  if (blk < 4096) {
    size_t i = ((size_t)blk * 256 + tid) * 4;
    float4 v = *(const float4*)&x[i];
    ushort4 u = make_ushort4(f2bf(v.x), f2bf(v.y), f2bf(v.z), f2bf(v.w));
    *(ushort4*)&x_bf[i] = u;
  } else if (blk < 7168) {
    int j = blk - 4096;
    wtrans_body(w_qkv, wqkvT, 1024, 3072, j % 96, j / 96, tid, tile);
  } else if (blk < 11264) {
    int j = blk - 7168;
    wtrans_body(w1, w1T, 1024, 4096, j & 127, j >> 7, tid, tile);
  } else if (blk < 15360) {
    int j = blk - 11264;
    wtrans_body(w2, w2T, 4096, 1024, j & 31, j >> 5, tid, tile);
  } else {
    int j = blk - 15360;
    wtrans_body(w_out, woutT, 1024, 1024, j & 31, j >> 5, tid, tile);
  }
}

// ---------------- 128x128 GEMM (2-barrier m97 structure, split-K capable) ----

template <bool GELU, bool STF32, bool STBF16>
__global__ __launch_bounds__(256)
void gemm128(const ushort* __restrict__ A, int lda,
             const ushort* __restrict__ BT, int ldb,
             const float* __restrict__ bias,
             float* __restrict__ Cf, ushort* __restrict__ Cb, int ldc, int K,
             size_t cstride) {
  __shared__ ushort lsa[128 * 64];
  __shared__ ushort lsb[128 * 64];
  const int tid = threadIdx.x;
  const int lane = tid & 63;
  const int wv = tid >> 6;
  const int wr = (wv >> 1) * 64, wc = (wv & 1) * 64;
  const size_t kStart = (size_t)blockIdx.z * K;
  const ushort* Ab = A + (size_t)blockIdx.y * 128 * lda + kStart;
  const ushort* Bb = BT + (size_t)blockIdx.x * 128 * ldb + kStart;
  f32x4 acc[4][4] = {};
  int rowS[4], slotS[4];
#pragma unroll
  for (int i = 0; i < 4; ++i) {
    int idx = tid + i * 256;
    rowS[i] = idx >> 3;
    slotS[i] = (idx & 7) ^ (rowS[i] & 7);
  }
  for (int kt = 0; kt < K; kt += 64) {
    __syncthreads();
#pragma unroll
    for (int i = 0; i < 4; ++i) {
      gl_lds16(Ab + (size_t)rowS[i] * lda + kt + slotS[i] * 8, &lsa[(tid + i * 256) * 8]);
      gl_lds16(Bb + (size_t)rowS[i] * ldb + kt + slotS[i] * 8, &lsb[(tid + i * 256) * 8]);
    }
    asm volatile("s_waitcnt vmcnt(0)" ::: "memory");
    __syncthreads();
#pragma unroll
    for (int kk = 0; kk < 2; ++kk) {
      bf16x8 af[4], bfr[4];
      const int g = kk * 4 + (lane >> 4);
#pragma unroll
      for (int m = 0; m < 4; ++m) {
        int r = wr + m * 16 + (lane & 15);
        af[m] = *(const bf16x8*)&lsa[r * 64 + ((g ^ (r & 7)) * 8)];
      }
#pragma unroll
      for (int n = 0; n < 4; ++n) {
        int r = wc + n * 16 + (lane & 15);
        bfr[n] = *(const bf16x8*)&lsb[r * 64 + ((g ^ (r & 7)) * 8)];
      }
#pragma unroll
      for (int m = 0; m < 4; ++m)
#pragma unroll
        for (int n = 0; n < 4; ++n)
          acc[m][n] = __builtin_amdgcn_mfma_f32_16x16x32_bf16(af[m], bfr[n], acc[m][n], 0, 0, 0);
    }
  }
  const int rb = blockIdx.y * 128 + wr + ((lane >> 4) << 2);
  const int cb = blockIdx.x * 128 + wc + (lane & 15);
  float* Cfz = Cf + (size_t)blockIdx.z * cstride;
  ushort* Cbz = Cb + (size_t)blockIdx.z * cstride;
#pragma unroll
  for (int m = 0; m < 4; ++m)
#pragma unroll
    for (int n = 0; n < 4; ++n) {
      int col = cb + n * 16;
      float bv = bias ? bias[col] : 0.0f;
#pragma unroll
      for (int i = 0; i < 4; ++i) {
        int row = rb + m * 16 + i;
        float v = acc[m][n][i] + bv;
        if (GELU) v = 0.5f * v * (1.0f + erff(v * 0.70710678f));
        if (STF32) Cfz[(size_t)row * ldc + col] = v;
        if (STBF16) Cbz[(size_t)row * ldc + col] = f2bf(v);
      }
    }
}

// ---------------- attention (split over KV, swapped-operand QK^T) ----------

DEVFN void attn_bid2(int& qb, int& bh, int& hf) {
  int lin = blockIdx.x;              // 0..1023
  int xcd = lin & 7;
  int idx = lin >> 3;
  int orig = xcd * 128 + idx;        // 128 contiguous per XCD = 4 bh values
  hf = orig & 1;
  qb = (orig >> 1) & 15;
  bh = orig >> 5;
}

__global__ __launch_bounds__(256, 4)
void attn_den_vt(const ushort* __restrict__ qkv, const float* __restrict__ rel_bias,
                 float* __restrict__ lsum, ushort* __restrict__ vT) {
  __shared__ ushort lsk[2][64 * 64];
  __shared__ float extb[1034];  // extb[k] = log2e*bias[clamp(k-3,0,1024)]
  __shared__ ushort vtile[64][72];
  const int tid = threadIdx.x;

  if (blockIdx.x >= 1024) {
    int j = blockIdx.x - 1024;
    int t0v = (j & 31) * 64;
    int bhv = j >> 5;
    int bv = bhv >> 4, hv = bhv & 15;
#pragma unroll
    for (int i = 0; i < 16; ++i) {
      int idx = tid + i * 256;
      int r = idx >> 6, c = idx & 63;
      vtile[r][c] = qkv[(size_t)(bv * 2048 + t0v + r) * 3072 + 2048 + hv * 64 + c];
    }
    __syncthreads();
#pragma unroll
    for (int i = 0; i < 16; ++i) {
      int idx = tid + i * 256;
      int d = idx >> 6, t = idx & 63;
      vT[((size_t)bhv * 64 + d) * 2048 + t0v + t] = vtile[t][d];
    }
    return;
  }

  const int lane = tid & 63;
  const int wv = tid >> 6;
  const int hi = lane >> 4;
  const int lo = lane & 15;
  int qb, bh, hf;
  attn_bid2(qb, bh, hf);
  const int b = bh >> 4, h = bh & 15;
  const int q0 = qb * 128;
  const int t0 = hf * 16;
  const ushort* qp = qkv + (size_t)b * 2048 * 3072 + h * 64;
  const ushort* kp = qp + 1024;
  const float C_SC = 0.18033688011f;  // 0.125 * log2(e)
  ushort* lsq = (ushort*)lsk;         // Q staged here pre-loop (16KB)

  for (int i = tid; i < 1034; i += 256) {
    int j = i - 3;
    j = j < 0 ? 0 : (j > 1024 ? 1024 : j);
    extb[i] = rel_bias[j * 16 + h] * 1.44269504f;
  }
#pragma unroll
  for (int i = 0; i < 4; ++i) {
    int idx = tid + i * 256;
    int row = idx >> 3;
    int slot = (idx & 7) ^ (row & 7);
    gl_lds16(qp + (size_t)(q0 + row) * 3072 + slot * 8, &lsq[idx * 8]);
  }
  WAITVM(0);
  WAITLGKM();
  BAR();
  bf16x8 qf[2][2];
#pragma unroll
  for (int mq = 0; mq < 2; ++mq)
#pragma unroll
    for (int kk = 0; kk < 2; ++kk) {
      int r = wv * 32 + mq * 16 + lo;
      int g = kk * 4 + hi;
      qf[mq][kk] = *(const bf16x8*)&lsq[r * 64 + ((g ^ (r & 7)) * 8)];
    }
  WAITLGKM();
  BAR();  // all waves hoisted before K staging overwrites

  const int r0 = tid >> 3;
  const int sl0 = (tid & 7) ^ (r0 & 7);
  const int r1 = (tid + 256) >> 3;
  const int sl1 = ((tid + 256) & 7) ^ (r1 & 7);
  auto stageK = [&](int t, int buf) {
    gl_lds16(kp + (size_t)(t * 64 + r0) * 3072 + sl0 * 8, &lsk[buf][tid * 8]);
    gl_lds16(kp + (size_t)(t * 64 + r1) * 3072 + sl1 * 8, &lsk[buf][(tid + 256) * 8]);
  };

  float l_part[2] = {0.0f, 0.0f};
  stageK(t0, 0);
  for (int t = t0; t < t0 + 16; ++t) {
    if (t < t0 + 15) {
      stageK(t + 1, (t + 1) & 1);
      WAITVM(2);
    } else {
      WAITVM(0);
    }
    BAR();
    f32x4 sacc[4][2] = {};
    __builtin_amdgcn_s_setprio(1);
#pragma unroll
    for (int kk = 0; kk < 2; ++kk) {
      const int g = kk * 4 + hi;
      bf16x8 ak[4];
#pragma unroll
      for (int mk = 0; mk < 4; ++mk) {
        int r = mk * 16 + lo;
        ak[mk] = *(const bf16x8*)&lsk[t & 1][r * 64 + ((g ^ (r & 7)) * 8)];
      }
#pragma unroll
      for (int mk = 0; mk < 4; ++mk)
#pragma unroll
        for (int mq = 0; mq < 2; ++mq)
          sacc[mk][mq] =
              __builtin_amdgcn_mfma_f32_16x16x32_bf16(ak[mk], qf[mq][kk], sacc[mk][mq], 0, 0, 0);
    }
    __builtin_amdgcn_s_setprio(0);
    const bool farR = (t * 64) >= q0 + 640;
    const bool farL = (t * 64 + 63) <= q0 - 512;
    if (farR || farL) {
      const float bc = farR ? extb[3 + 1024] : extb[3];
#pragma unroll
      for (int mq = 0; mq < 2; ++mq) {
        float s = 0.0f;
#pragma unroll
        for (int mk = 0; mk < 4; ++mk)
#pragma unroll
          for (int i = 0; i < 4; ++i)
            s += exp2f_fast(fmaf(sacc[mk][mq][i], C_SC, bc));
        l_part[mq] += s;
      }
    } else {
      const int kbase = t * 64 + hi * 4;
      const int qr = q0 + wv * 32 + lo;
#pragma unroll
      for (int mq = 0; mq < 2; ++mq) {
        float s = 0.0f;
#pragma unroll
        for (int mk = 0; mk < 4; ++mk) {
          int k0 = (kbase + mk * 16) - (qr + mq * 16) + 515;
          k0 = k0 < 0 ? 0 : (k0 > 1030 ? 1030 : k0);
#pragma unroll
          for (int i = 0; i < 4; ++i)
            s += exp2f_fast(fmaf(sacc[mk][mq][i], C_SC, extb[k0 + i]));
        }
        l_part[mq] += s;
      }
    }
    BAR();
  }

#pragma unroll
  for (int mq = 0; mq < 2; ++mq) {
    float l = l_part[mq];
    l += __shfl_xor(l, 16);
    l += __shfl_xor(l, 32);
    if (hi == 0)
      lsum[(size_t)hf * 65536 + (size_t)bh * 2048 + q0 + wv * 32 + mq * 16 + lo] = l;
  }
}

__global__ __launch_bounds__(256, 3)
void attn_pv2(const ushort* __restrict__ qkv, const ushort* __restrict__ vT,
              const float* __restrict__ rel_bias, const float* __restrict__ lsum,
              float* __restrict__ attn, ushort* __restrict__ opart) {
  __shared__ ushort lsk[2][64 * 64];
  __shared__ ushort lsv[2][64 * 64];
  __shared__ ushort lsp[128 * 64];
  __shared__ float extb[1034];
  const int tid = threadIdx.x;
  const int lane = tid & 63;
  const int wv = tid >> 6;
  const int hi = lane >> 4;
  const int lo = lane & 15;
  int qb, bh, hf;
  attn_bid2(qb, bh, hf);
  const int b = bh >> 4, h = bh & 15;
  const int q0 = qb * 128;
  const int t0 = hf * 16;
  const ushort* qp = qkv + (size_t)b * 2048 * 3072 + h * 64;
  const ushort* kp = qp + 1024;
  const ushort* vp = vT + (size_t)bh * 64 * 2048;
  float* attnb = attn + (size_t)bh * 2048 * 2048;
  const float C_SC = 0.18033688011f;

  for (int i = tid; i < 1034; i += 256) {
    int j = i - 3;
    j = j < 0 ? 0 : (j > 1024 ? 1024 : j);
    extb[i] = rel_bias[j * 16 + h] * 1.44269504f;
  }
#pragma unroll
  for (int i = 0; i < 4; ++i) {
    int idx = tid + i * 256;
    int row = idx >> 3;
    int slot = (idx & 7) ^ (row & 7);
    gl_lds16(qp + (size_t)(q0 + row) * 3072 + slot * 8, &lsp[idx * 8]);
  }
  WAITVM(0);
  WAITLGKM();
  BAR();
  bf16x8 qf[2][2];
#pragma unroll
  for (int mq = 0; mq < 2; ++mq)
#pragma unroll
    for (int kk = 0; kk < 2; ++kk) {
      int r = wv * 32 + mq * 16 + lo;
      int g = kk * 4 + hi;
      qf[mq][kk] = *(const bf16x8*)&lsp[r * 64 + ((g ^ (r & 7)) * 8)];
    }
  WAITLGKM();
  BAR();  // all waves hoisted before lsp is overwritten by P

  float il[2];
#pragma unroll
  for (int mq = 0; mq < 2; ++mq) {
    size_t qi = (size_t)bh * 2048 + q0 + wv * 32 + mq * 16 + lo;
    il[mq] = 1.0f / (lsum[qi] + lsum[qi + 65536]);
  }

  const int r0 = tid >> 3;
  const int sl0 = (tid & 7) ^ (r0 & 7);
  const int r1 = (tid + 256) >> 3;
  const int sl1 = ((tid + 256) & 7) ^ (r1 & 7);
  auto stageK = [&](int t, int buf) {
    gl_lds16(kp + (size_t)(t * 64 + r0) * 3072 + sl0 * 8, &lsk[buf][tid * 8]);
    gl_lds16(kp + (size_t)(t * 64 + r1) * 3072 + sl1 * 8, &lsk[buf][(tid + 256) * 8]);
  };
  auto stageV = [&](int t, int buf) {
    gl_lds16(vp + (size_t)r0 * 2048 + t * 64 + sl0 * 8, &lsv[buf][tid * 8]);
    gl_lds16(vp + (size_t)r1 * 2048 + t * 64 + sl1 * 8, &lsv[buf][(tid + 256) * 8]);
  };

  f32x4 acc_o[2][4] = {};
  stageK(t0, 0);
  stageV(t0, 0);
  for (int t = t0; t < t0 + 16; ++t) {
    if (t < t0 + 15) {
      stageK(t + 1, (t + 1) & 1);
      stageV(t + 1, (t + 1) & 1);
    }
    if (t == t0) { WAITVM(4); }
    else if (t < t0 + 15) { WAITVM(12); }
    else { WAITVM(8); }
    BAR();
    f32x4 sacc[4][2] = {};
    __builtin_amdgcn_s_setprio(1);
#pragma unroll
    for (int kk = 0; kk < 2; ++kk) {
      const int g = kk * 4 + hi;
      bf16x8 ak[4];
#pragma unroll
      for (int mk = 0; mk < 4; ++mk) {
        int r = mk * 16 + lo;
        ak[mk] = *(const bf16x8*)&lsk[t & 1][r * 64 + ((g ^ (r & 7)) * 8)];
      }
#pragma unroll
      for (int mk = 0; mk < 4; ++mk)
#pragma unroll
        for (int mq = 0; mq < 2; ++mq)
          sacc[mk][mq] =
              __builtin_amdgcn_mfma_f32_16x16x32_bf16(ak[mk], qf[mq][kk], sacc[mk][mq], 0, 0, 0);
    }
    __builtin_amdgcn_s_setprio(0);
    const bool farR = (t * 64) >= q0 + 640;
    const bool farT = farR || ((t * 64 + 63) <= q0 - 512);
    const float bcf = farR ? extb[3 + 1024] : extb[3];
#pragma unroll
    for (int mq = 0; mq < 2; ++mq) {
      const int row = wv * 32 + mq * 16 + lo;  // local q-row
      const float l = il[mq];
#pragma unroll
      for (int mk = 0; mk < 4; ++mk) {
        const int c0 = mk * 16 + hi * 4;  // local k-col base (4-aligned)
        float p4[4];
        if (farT) {
#pragma unroll
          for (int i = 0; i < 4; ++i)
            p4[i] = exp2f_fast(fmaf(sacc[mk][mq][i], C_SC, bcf)) * l;
        } else {
          int k0 = (t * 64 + c0) - (q0 + row) + 515;
          k0 = k0 < 0 ? 0 : (k0 > 1030 ? 1030 : k0);
#pragma unroll
          for (int i = 0; i < 4; ++i)
            p4[i] = exp2f_fast(fmaf(sacc[mk][mq][i], C_SC, extb[k0 + i])) * l;
        }
        ushort4 u = make_ushort4(f2bf(p4[0]), f2bf(p4[1]), f2bf(p4[2]), f2bf(p4[3]));
        *(ushort4*)&lsp[row * 64 + (((c0 >> 3) ^ (row & 7)) << 3) + (c0 & 7)] = u;
        *(float4*)&attnb[(size_t)(q0 + row) * 2048 + t * 64 + c0] =
            make_float4(p4[0], p4[1], p4[2], p4[3]);
      }
    }
    WAITLGKM();
    BAR();
    __builtin_amdgcn_s_setprio(1);
#pragma unroll
    for (int kk = 0; kk < 2; ++kk) {
      const int g = kk * 4 + hi;
      bf16x8 ap[2], bv2[4];
#pragma unroll
      for (int m = 0; m < 2; ++m) {
        int r = wv * 32 + m * 16 + lo;
        ap[m] = *(const bf16x8*)&lsp[r * 64 + ((g ^ (r & 7)) * 8)];
      }
#pragma unroll
      for (int n = 0; n < 4; ++n) {
        int r = n * 16 + lo;
        bv2[n] = *(const bf16x8*)&lsv[t & 1][r * 64 + ((g ^ (r & 7)) * 8)];
      }
#pragma unroll
      for (int m = 0; m < 2; ++m)
#pragma unroll
        for (int n = 0; n < 4; ++n)
          acc_o[m][n] = __builtin_amdgcn_mfma_f32_16x16x32_bf16(ap[m], bv2[n], acc_o[m][n], 0, 0, 0);
    }
    __builtin_amdgcn_s_setprio(0);
  }

  // epilogue: partial O (bf16) -> opart[hf]
  ushort* ob = opart + (size_t)hf * 4194304;
#pragma unroll
  for (int m = 0; m < 2; ++m)
#pragma unroll
    for (int n = 0; n < 4; ++n) {
      int col = h * 64 + n * 16 + lo;
#pragma unroll
      for (int i = 0; i < 4; ++i) {
        int row = q0 + wv * 32 + m * 16 + (hi << 2) + i;
        ob[(size_t)(b * 2048 + row) * 1024 + col] = f2bf(acc_o[m][n][i]);
      }
    }
}

// ctx = bf16(O0 + O1)  (bf16 partials)
__global__ __launch_bounds__(256) void ocomb(const ushort* __restrict__ opart,
                                             ushort* __restrict__ ctx) {
  size_t i = ((size_t)blockIdx.x * 256 + threadIdx.x) * 4;
  ushort4 a = *(const ushort4*)&opart[i];
  ushort4 c = *(const ushort4*)&opart[4194304 + i];
  ushort4 u = make_ushort4(f2bf(bf2f(a.x) + bf2f(c.x)), f2bf(bf2f(a.y) + bf2f(c.y)),
                           f2bf(bf2f(a.z) + bf2f(c.z)), f2bf(bf2f(a.w) + bf2f(c.w)));
  *(ushort4*)&ctx[i] = u;
}

// ---------------- residual(s) + bias + layernorm ----------------
// x = base(f32 af or bf16 ab) + r0 + r1? + r2? + r3? + bias? ; y = LN(x)*g+be

__global__ __launch_bounds__(256)
void add_ln(const float* __restrict__ af, const ushort* __restrict__ ab,
            const float* __restrict__ r0, const float* __restrict__ r1,
            const float* __restrict__ r2, const float* __restrict__ r3,
            const float* __restrict__ bias,
            const float* __restrict__ g, const float* __restrict__ be,
            float* __restrict__ outf, ushort* __restrict__ outb) {
  const int tid = threadIdx.x;
  const size_t base = (size_t)blockIdx.x * 1024 + tid * 4;
  float x0, x1, x2, x3;
  if (af) {
    float4 va = *(const float4*)&af[base];
    x0 = va.x; x1 = va.y; x2 = va.z; x3 = va.w;
  } else {
    ushort4 ua = *(const ushort4*)&ab[base];
    x0 = bf2f(ua.x); x1 = bf2f(ua.y); x2 = bf2f(ua.z); x3 = bf2f(ua.w);
  }
  {
    float4 vr = *(const float4*)&r0[base];
    x0 += vr.x; x1 += vr.y; x2 += vr.z; x3 += vr.w;
  }
  if (r1) {
    float4 v1 = *(const float4*)&r1[base];
    x0 += v1.x; x1 += v1.y; x2 += v1.z; x3 += v1.w;
  }
  if (r2) {
    float4 v2 = *(const float4*)&r2[base];
    x0 += v2.x; x1 += v2.y; x2 += v2.z; x3 += v2.w;
  }
  if (r3) {
    float4 v3 = *(const float4*)&r3[base];
    x0 += v3.x; x1 += v3.y; x2 += v3.z; x3 += v3.w;
  }
  if (bias) {
    float4 vb4 = *(const float4*)&bias[tid * 4];
    x0 += vb4.x; x1 += vb4.y; x2 += vb4.z; x3 += vb4.w;
  }
  float s = x0 + x1 + x2 + x3;
  float s2 = x0 * x0 + x1 * x1 + x2 * x2 + x3 * x3;
  s = wred_sum(s);
  s2 = wred_sum(s2);
  __shared__ float rs[4], rq[4];
  if ((tid & 63) == 0) { rs[tid >> 6] = s; rq[tid >> 6] = s2; }
  __syncthreads();
  s = rs[0] + rs[1] + rs[2] + rs[3];
  s2 = rq[0] + rq[1] + rq[2] + rq[3];
  const float mean = s * (1.0f / 1024.0f);
  const float var = s2 * (1.0f / 1024.0f) - mean * mean;
  const float sc = rsqrtf(var + 1e-5f);
  float4 vg = *(const float4*)&g[tid * 4];
  float4 vb = *(const float4*)&be[tid * 4];
  float y0 = (x0 - mean) * sc * vg.x + vb.x;
  float y1 = (x1 - mean) * sc * vg.y + vb.y;
  float y2 = (x2 - mean) * sc * vg.z + vb.z;
  float y3 = (x3 - mean) * sc * vg.w + vb.w;
  if (outf) *(float4*)&outf[base] = make_float4(y0, y1, y2, y3);
  if (outb) {
    ushort4 u = make_ushort4(f2bf(y0), f2bf(y1), f2bf(y2), f2bf(y3));
    *(ushort4*)&outb[base] = u;
  }
}

// ---------------- launch ----------------

extern "C" void kernel_launch(void* const* d_in, const int* in_sizes, int n_in,
                              void* d_out, int out_size, void* d_ws, size_t ws_size,
                              hipStream_t stream) {
  const float* x     = (const float*)d_in[0];
  const float* w_qkv = (const float*)d_in[1];
  const float* b_qkv = (const float*)d_in[2];
  const float* w_out = (const float*)d_in[3];
  const float* b_out = (const float*)d_in[4];
  const float* relb  = (const float*)d_in[5];
  const float* g1    = (const float*)d_in[6];
  const float* be1   = (const float*)d_in[7];
  const float* w1    = (const float*)d_in[8];
  const float* b1    = (const float*)d_in[9];
  const float* w2    = (const float*)d_in[10];
  const float* b2    = (const float*)d_in[11];
  const float* g2    = (const float*)d_in[12];
  const float* be2   = (const float*)d_in[13];

  float* x3o  = (float*)d_out;
  float* attn = x3o + (size_t)4194304;

  char* w = (char*)d_ws;
  size_t off = 0;
  auto alloc = [&](size_t bytes) {
    void* p = w + off;
    off += (bytes + 255) & ~(size_t)255;
    return p;
  };
  ushort* x_bf   = (ushort*)alloc(4096ull * 1024 * 2);
  ushort* wqkvT  = (ushort*)alloc(3072ull * 1024 * 2);
  ushort* woutT  = (ushort*)alloc(1024ull * 1024 * 2);
  ushort* w1T    = (ushort*)alloc(4096ull * 1024 * 2);
  ushort* w2T    = (ushort*)alloc(1024ull * 4096 * 2);
  ushort* qkv_bf = (ushort*)alloc(4096ull * 3072 * 2);
  ushort* vT     = (ushort*)alloc(32ull * 64 * 2048 * 2);
  ushort* ctx_bf = (ushort*)alloc(4096ull * 1024 * 2);
  float*  lsum   = (float*)alloc(2ull * 32 * 2048 * 4);
  ushort* opart  = (ushort*)alloc(2ull * 4096 * 1024 * 2);
  float*  p0     = (float*)alloc(4096ull * 1024 * 4);
  float*  p1     = (float*)alloc(4096ull * 1024 * 4);
  float*  p2     = (float*)alloc(4096ull * 1024 * 4);
  float*  p3     = (float*)alloc(4096ull * 1024 * 4);
  ushort* x2bf   = (ushort*)alloc(4096ull * 1024 * 2);
  ushort* ff1_bf = (ushort*)alloc(4096ull * 4096 * 2);

  prep<<<16384, 256, 0, stream>>>(x, x_bf, w_qkv, wqkvT, w1, w1T, w2, w2T,
                                  w_out, woutT);
  gemm128<false, false, true><<<dim3(24, 32), 256, 0, stream>>>(
      x_bf, 1024, wqkvT, 1024, b_qkv, nullptr, qkv_bf, 3072, 1024, 0);
  attn_den_vt<<<2048, 256, 0, stream>>>(qkv_bf, relb, lsum, vT);
  attn_pv2<<<1024, 256, 0, stream>>>(qkv_bf, vT, relb, lsum, attn, opart);
  ocomb<<<4096, 256, 0, stream>>>(opart, ctx_bf);

  // out-proj: split-K x2 (K=1024 -> 2x512), partials p0/p1; bias folded into LN1
  gemm128<false, true, false><<<dim3(8, 32, 2), 256, 0, stream>>>(
      ctx_bf, 1024, woutT, 1024, nullptr, p0, nullptr, 1024, 512,
      (size_t)(p1 - p0));
  // LN1: x2 = LN(x + p0 + p1 + b_out); emit bf16 only (LN2 reuses x2bf as residual)
  add_ln<<<4096, 256, 0, stream>>>(x, nullptr, p0, p1, nullptr, nullptr, b_out,
                                   g1, be1, nullptr, x2bf);
  gemm128<true, false, true><<<dim3(32, 32), 256, 0, stream>>>(
      x2bf, 1024, w1T, 1024, b1, nullptr, ff1_bf, 4096, 1024, 0);
  // ff2: split-K x4 (K=4096 -> 4x1024), partials p0..p3; bias folded into LN2
  gemm128<false, true, false><<<dim3(8, 32, 4), 256, 0, stream>>>(
      ff1_bf, 4096, w2T, 4096, nullptr, p0, nullptr, 1024, 1024,
      (size_t)(p1 - p0));
  add_ln<<<4096, 256, 0, stream>>>(nullptr, x2bf, p0, p1, p2, p3, b2,
                                   g2, be2, x3o, nullptr);
}

// Round 12
// 431.321 us; speedup vs baseline: 1.0480x; 1.0480x over previous
//
#include <hip/hip_runtime.h>
#include <hip/hip_bf16.h>
#include <cstdint>
#include <cstddef>

#define DEVFN static __device__ __forceinline__

typedef __attribute__((ext_vector_type(8))) short bf16x8;
typedef __attribute__((ext_vector_type(4))) float f32x4;

#define WAITVM(N) asm volatile("s_waitcnt vmcnt(" #N ")" ::: "memory")
#define WAITLGKM() asm volatile("s_waitcnt lgkmcnt(0)" ::: "memory")
#define BAR() __builtin_amdgcn_s_barrier()

DEVFN float exp2f_fast(float x) { return __builtin_amdgcn_exp2f(x); }

DEVFN ushort f2bf(float f) {
  uint32_t u = __float_as_uint(f);
  return (ushort)((u + 0x7fffu + ((u >> 16) & 1u)) >> 16);
}
DEVFN float bf2f(ushort u) { return __uint_as_float((uint32_t)u << 16); }

DEVFN void gl_lds16(const void* g, void* l) {
  __builtin_amdgcn_global_load_lds(
      (const __attribute__((address_space(1))) void*)g,
      (__attribute__((address_space(3))) void*)l, 16, 0, 0);
}

DEVFN float wred_sum(float v) {
#pragma unroll
  for (int o = 32; o; o >>= 1) v += __shfl_xor(v, o);
  return v;
}

// ---------------- fused prep: pack x + all 4 weight transposes ----------------

DEVFN void wtrans_body(const float* __restrict__ in, ushort* __restrict__ out,
                       int K, int N, int bx, int by, int tid, float* tile /*32*33*/) {
  int n0 = bx * 32, k0 = by * 32;
#pragma unroll
  for (int i = 0; i < 4; ++i) {
    int idx = tid + i * 256;
    int r = idx >> 5, c = idx & 31;
    tile[r * 33 + c] = in[(size_t)(k0 + r) * N + n0 + c];
  }
  __syncthreads();
#pragma unroll
  for (int i = 0; i < 4; ++i) {
    int idx = tid + i * 256;
    int r = idx >> 5, c = idx & 31;
    out[(size_t)(n0 + r) * K + k0 + c] = f2bf(tile[c * 33 + r]);
  }
}

__global__ __launch_bounds__(256)
void prep(const float* __restrict__ x, ushort* __restrict__ x_bf,
          const float* __restrict__ w_qkv, ushort* __restrict__ wqkvT,
          const float* __restrict__ w1, ushort* __restrict__ w1T,
          const float* __restrict__ w2, ushort* __restrict__ w2T,
          const float* __restrict__ w_out, ushort* __restrict__ woutT) {
  __shared__ float tile[32 * 33];
  const int blk = blockIdx.x;
  const int tid = threadIdx.x;
  if (blk < 4096) {
    size_t i = ((size_t)blk * 256 + tid) * 4;
    float4 v = *(const float4*)&x[i];
    ushort4 u = make_ushort4(f2bf(v.x), f2bf(v.y), f2bf(v.z), f2bf(v.w));
    *(ushort4*)&x_bf[i] = u;
  } else if (blk < 7168) {
    int j = blk - 4096;
    wtrans_body(w_qkv, wqkvT, 1024, 3072, j % 96, j / 96, tid, tile);
  } else if (blk < 11264) {
    int j = blk - 7168;
    wtrans_body(w1, w1T, 1024, 4096, j & 127, j >> 7, tid, tile);
  } else if (blk < 15360) {
    int j = blk - 11264;
    wtrans_body(w2, w2T, 4096, 1024, j & 31, j >> 5, tid, tile);
  } else {
    int j = blk - 15360;
    wtrans_body(w_out, woutT, 1024, 1024, j & 31, j >> 5, tid, tile);
  }
}

// ---------------- 128x128 GEMM (2-barrier m97 structure, split-K capable) ----

template <bool GELU, bool STF32, bool STBF16>
__global__ __launch_bounds__(256)
void gemm128(const ushort* __restrict__ A, int lda,
             const ushort* __restrict__ BT, int ldb,
             const float* __restrict__ bias,
             float* __restrict__ Cf, ushort* __restrict__ Cb, int ldc, int K,
             size_t cstride) {
  __shared__ ushort lsa[128 * 64];
  __shared__ ushort lsb[128 * 64];
  const int tid = threadIdx.x;
  const int lane = tid & 63;
  const int wv = tid >> 6;
  const int wr = (wv >> 1) * 64, wc = (wv & 1) * 64;
  const size_t kStart = (size_t)blockIdx.z * K;
  const ushort* Ab = A + (size_t)blockIdx.y * 128 * lda + kStart;
  const ushort* Bb = BT + (size_t)blockIdx.x * 128 * ldb + kStart;
  f32x4 acc[4][4] = {};
  int rowS[4], slotS[4];
#pragma unroll
  for (int i = 0; i < 4; ++i) {
    int idx = tid + i * 256;
    rowS[i] = idx >> 3;
    slotS[i] = (idx & 7) ^ (rowS[i] & 7);
  }
  for (int kt = 0; kt < K; kt += 64) {
    __syncthreads();
#pragma unroll
    for (int i = 0; i < 4; ++i) {
      gl_lds16(Ab + (size_t)rowS[i] * lda + kt + slotS[i] * 8, &lsa[(tid + i * 256) * 8]);
      gl_lds16(Bb + (size_t)rowS[i] * ldb + kt + slotS[i] * 8, &lsb[(tid + i * 256) * 8]);
    }
    asm volatile("s_waitcnt vmcnt(0)" ::: "memory");
    __syncthreads();
#pragma unroll
    for (int kk = 0; kk < 2; ++kk) {
      bf16x8 af[4], bfr[4];
      const int g = kk * 4 + (lane >> 4);
#pragma unroll
      for (int m = 0; m < 4; ++m) {
        int r = wr + m * 16 + (lane & 15);
        af[m] = *(const bf16x8*)&lsa[r * 64 + ((g ^ (r & 7)) * 8)];
      }
#pragma unroll
      for (int n = 0; n < 4; ++n) {
        int r = wc + n * 16 + (lane & 15);
        bfr[n] = *(const bf16x8*)&lsb[r * 64 + ((g ^ (r & 7)) * 8)];
      }
#pragma unroll
      for (int m = 0; m < 4; ++m)
#pragma unroll
        for (int n = 0; n < 4; ++n)
          acc[m][n] = __builtin_amdgcn_mfma_f32_16x16x32_bf16(af[m], bfr[n], acc[m][n], 0, 0, 0);
    }
  }
  const int rb = blockIdx.y * 128 + wr + ((lane >> 4) << 2);
  const int cb = blockIdx.x * 128 + wc + (lane & 15);
  float* Cfz = Cf + (size_t)blockIdx.z * cstride;
  ushort* Cbz = Cb + (size_t)blockIdx.z * cstride;
#pragma unroll
  for (int m = 0; m < 4; ++m)
#pragma unroll
    for (int n = 0; n < 4; ++n) {
      int col = cb + n * 16;
      float bv = bias ? bias[col] : 0.0f;
#pragma unroll
      for (int i = 0; i < 4; ++i) {
        int row = rb + m * 16 + i;
        float v = acc[m][n][i] + bv;
        if (GELU) v = 0.5f * v * (1.0f + erff(v * 0.70710678f));
        if (STF32) Cfz[(size_t)row * ldc + col] = v;
        if (STBF16) Cbz[(size_t)row * ldc + col] = f2bf(v);
      }
    }
}

// ---------------- attention (split over KV, swapped-operand QK^T) ----------

DEVFN void attn_bid2(int& qb, int& bh, int& hf) {
  int lin = blockIdx.x;              // 0..1023
  int xcd = lin & 7;
  int idx = lin >> 3;
  int orig = xcd * 128 + idx;        // 128 contiguous per XCD = 4 bh values
  hf = orig & 1;
  qb = (orig >> 1) & 15;
  bh = orig >> 5;
}

__global__ __launch_bounds__(256, 4)
void attn_den_vt(const ushort* __restrict__ qkv, const float* __restrict__ rel_bias,
                 float* __restrict__ lsum, ushort* __restrict__ vT) {
  __shared__ ushort lsk[2][64 * 64];
  __shared__ float extb[1034];  // extb[k] = log2e*bias[clamp(k-3,0,1024)]
  __shared__ ushort vtile[64][72];
  const int tid = threadIdx.x;

  if (blockIdx.x >= 1024) {
    int j = blockIdx.x - 1024;
    int t0v = (j & 31) * 64;
    int bhv = j >> 5;
    int bv = bhv >> 4, hv = bhv & 15;
#pragma unroll
    for (int i = 0; i < 16; ++i) {
      int idx = tid + i * 256;
      int r = idx >> 6, c = idx & 63;
      vtile[r][c] = qkv[(size_t)(bv * 2048 + t0v + r) * 3072 + 2048 + hv * 64 + c];
    }
    __syncthreads();
#pragma unroll
    for (int i = 0; i < 16; ++i) {
      int idx = tid + i * 256;
      int d = idx >> 6, t = idx & 63;
      vT[((size_t)bhv * 64 + d) * 2048 + t0v + t] = vtile[t][d];
    }
    return;
  }

  const int lane = tid & 63;
  const int wv = tid >> 6;
  const int hi = lane >> 4;
  const int lo = lane & 15;
  int qb, bh, hf;
  attn_bid2(qb, bh, hf);
  const int b = bh >> 4, h = bh & 15;
  const int q0 = qb * 128;
  const int t0 = hf * 16;
  const ushort* qp = qkv + (size_t)b * 2048 * 3072 + h * 64;
  const ushort* kp = qp + 1024;
  const float C_SC = 0.18033688011f;  // 0.125 * log2(e)
  ushort* lsq = (ushort*)lsk;         // Q staged here pre-loop (16KB)

  for (int i = tid; i < 1034; i += 256) {
    int j = i - 3;
    j = j < 0 ? 0 : (j > 1024 ? 1024 : j);
    extb[i] = rel_bias[j * 16 + h] * 1.44269504f;
  }
#pragma unroll
  for (int i = 0; i < 4; ++i) {
    int idx = tid + i * 256;
    int row = idx >> 3;
    int slot = (idx & 7) ^ (row & 7);
    gl_lds16(qp + (size_t)(q0 + row) * 3072 + slot * 8, &lsq[idx * 8]);
  }
  WAITVM(0);
  WAITLGKM();
  BAR();
  bf16x8 qf[2][2];
#pragma unroll
  for (int mq = 0; mq < 2; ++mq)
#pragma unroll
    for (int kk = 0; kk < 2; ++kk) {
      int r = wv * 32 + mq * 16 + lo;
      int g = kk * 4 + hi;
      qf[mq][kk] = *(const bf16x8*)&lsq[r * 64 + ((g ^ (r & 7)) * 8)];
    }
  WAITLGKM();
  BAR();  // all waves hoisted before K staging overwrites

  const int r0 = tid >> 3;
  const int sl0 = (tid & 7) ^ (r0 & 7);
  const int r1 = (tid + 256) >> 3;
  const int sl1 = ((tid + 256) & 7) ^ (r1 & 7);
  auto stageK = [&](int t, int buf) {
    gl_lds16(kp + (size_t)(t * 64 + r0) * 3072 + sl0 * 8, &lsk[buf][tid * 8]);
    gl_lds16(kp + (size_t)(t * 64 + r1) * 3072 + sl1 * 8, &lsk[buf][(tid + 256) * 8]);
  };

  float l_part[2] = {0.0f, 0.0f};
  stageK(t0, 0);
  for (int t = t0; t < t0 + 16; ++t) {
    if (t < t0 + 15) {
      stageK(t + 1, (t + 1) & 1);
      WAITVM(2);
    } else {
      WAITVM(0);
    }
    BAR();
    f32x4 sacc[4][2] = {};
    __builtin_amdgcn_s_setprio(1);
#pragma unroll
    for (int kk = 0; kk < 2; ++kk) {
      const int g = kk * 4 + hi;
      bf16x8 ak[4];
#pragma unroll
      for (int mk = 0; mk < 4; ++mk) {
        int r = mk * 16 + lo;
        ak[mk] = *(const bf16x8*)&lsk[t & 1][r * 64 + ((g ^ (r & 7)) * 8)];
      }
#pragma unroll
      for (int mk = 0; mk < 4; ++mk)
#pragma unroll
        for (int mq = 0; mq < 2; ++mq)
          sacc[mk][mq] =
              __builtin_amdgcn_mfma_f32_16x16x32_bf16(ak[mk], qf[mq][kk], sacc[mk][mq], 0, 0, 0);
    }
    __builtin_amdgcn_s_setprio(0);
    const bool farR = (t * 64) >= q0 + 640;
    const bool farL = (t * 64 + 63) <= q0 - 512;
    if (farR || farL) {
      const float bc = farR ? extb[3 + 1024] : extb[3];
#pragma unroll
      for (int mq = 0; mq < 2; ++mq) {
        float s = 0.0f;
#pragma unroll
        for (int mk = 0; mk < 4; ++mk)
#pragma unroll
          for (int i = 0; i < 4; ++i)
            s += exp2f_fast(fmaf(sacc[mk][mq][i], C_SC, bc));
        l_part[mq] += s;
      }
    } else {
      const int kbase = t * 64 + hi * 4;
      const int qr = q0 + wv * 32 + lo;
#pragma unroll
      for (int mq = 0; mq < 2; ++mq) {
        float s = 0.0f;
#pragma unroll
        for (int mk = 0; mk < 4; ++mk) {
          int k0 = (kbase + mk * 16) - (qr + mq * 16) + 515;
          k0 = k0 < 0 ? 0 : (k0 > 1030 ? 1030 : k0);
#pragma unroll
          for (int i = 0; i < 4; ++i)
            s += exp2f_fast(fmaf(sacc[mk][mq][i], C_SC, extb[k0 + i]));
        }
        l_part[mq] += s;
      }
    }
    BAR();
  }

#pragma unroll
  for (int mq = 0; mq < 2; ++mq) {
    float l = l_part[mq];
    l += __shfl_xor(l, 16);
    l += __shfl_xor(l, 32);
    if (hi == 0)
      lsum[(size_t)hf * 65536 + (size_t)bh * 2048 + q0 + wv * 32 + mq * 16 + lo] = l;
  }
}

__global__ __launch_bounds__(256, 3)
void attn_pv2(const ushort* __restrict__ qkv, const ushort* __restrict__ vT,
              const float* __restrict__ rel_bias, const float* __restrict__ lsum,
              float* __restrict__ attn, ushort* __restrict__ opart) {
  __shared__ ushort lsk[2][64 * 64];
  __shared__ ushort lsv[2][64 * 64];
  __shared__ ushort lsp[128 * 64];
  __shared__ float extb[1034];
  const int tid = threadIdx.x;
  const int lane = tid & 63;
  const int wv = tid >> 6;
  const int hi = lane >> 4;
  const int lo = lane & 15;
  int qb, bh, hf;
  attn_bid2(qb, bh, hf);
  const int b = bh >> 4, h = bh & 15;
  const int q0 = qb * 128;
  const int t0 = hf * 16;
  const ushort* qp = qkv + (size_t)b * 2048 * 3072 + h * 64;
  const ushort* kp = qp + 1024;
  const ushort* vp = vT + (size_t)bh * 64 * 2048;
  float* attnb = attn + (size_t)bh * 2048 * 2048;
  const float C_SC = 0.18033688011f;

  for (int i = tid; i < 1034; i += 256) {
    int j = i - 3;
    j = j < 0 ? 0 : (j > 1024 ? 1024 : j);
    extb[i] = rel_bias[j * 16 + h] * 1.44269504f;
  }
#pragma unroll
  for (int i = 0; i < 4; ++i) {
    int idx = tid + i * 256;
    int row = idx >> 3;
    int slot = (idx & 7) ^ (row & 7);
    gl_lds16(qp + (size_t)(q0 + row) * 3072 + slot * 8, &lsp[idx * 8]);
  }
  WAITVM(0);
  WAITLGKM();
  BAR();
  bf16x8 qf[2][2];
#pragma unroll
  for (int mq = 0; mq < 2; ++mq)
#pragma unroll
    for (int kk = 0; kk < 2; ++kk) {
      int r = wv * 32 + mq * 16 + lo;
      int g = kk * 4 + hi;
      qf[mq][kk] = *(const bf16x8*)&lsp[r * 64 + ((g ^ (r & 7)) * 8)];
    }
  WAITLGKM();
  BAR();  // all waves hoisted before lsp is overwritten by P

  float il[2];
#pragma unroll
  for (int mq = 0; mq < 2; ++mq) {
    size_t qi = (size_t)bh * 2048 + q0 + wv * 32 + mq * 16 + lo;
    il[mq] = 1.0f / (lsum[qi] + lsum[qi + 65536]);
  }

  const int r0 = tid >> 3;
  const int sl0 = (tid & 7) ^ (r0 & 7);
  const int r1 = (tid + 256) >> 3;
  const int sl1 = ((tid + 256) & 7) ^ (r1 & 7);
  auto stageK = [&](int t, int buf) {
    gl_lds16(kp + (size_t)(t * 64 + r0) * 3072 + sl0 * 8, &lsk[buf][tid * 8]);
    gl_lds16(kp + (size_t)(t * 64 + r1) * 3072 + sl1 * 8, &lsk[buf][(tid + 256) * 8]);
  };
  auto stageV = [&](int t, int buf) {
    gl_lds16(vp + (size_t)r0 * 2048 + t * 64 + sl0 * 8, &lsv[buf][tid * 8]);
    gl_lds16(vp + (size_t)r1 * 2048 + t * 64 + sl1 * 8, &lsv[buf][(tid + 256) * 8]);
  };

  f32x4 acc_o[2][4] = {};
  stageK(t0, 0);
  stageV(t0, 0);
  for (int t = t0; t < t0 + 16; ++t) {
    if (t < t0 + 15) {
      stageK(t + 1, (t + 1) & 1);
      stageV(t + 1, (t + 1) & 1);
    }
    if (t == t0) { WAITVM(4); }
    else if (t < t0 + 15) { WAITVM(12); }
    else { WAITVM(8); }
    BAR();
    f32x4 sacc[4][2] = {};
    __builtin_amdgcn_s_setprio(1);
#pragma unroll
    for (int kk = 0; kk < 2; ++kk) {
      const int g = kk * 4 + hi;
      bf16x8 ak[4];
#pragma unroll
      for (int mk = 0; mk < 4; ++mk) {
        int r = mk * 16 + lo;
        ak[mk] = *(const bf16x8*)&lsk[t & 1][r * 64 + ((g ^ (r & 7)) * 8)];
      }
#pragma unroll
      for (int mk = 0; mk < 4; ++mk)
#pragma unroll
        for (int mq = 0; mq < 2; ++mq)
          sacc[mk][mq] =
              __builtin_amdgcn_mfma_f32_16x16x32_bf16(ak[mk], qf[mq][kk], sacc[mk][mq], 0, 0, 0);
    }
    __builtin_amdgcn_s_setprio(0);
    const bool farR = (t * 64) >= q0 + 640;
    const bool farT = farR || ((t * 64 + 63) <= q0 - 512);
    const float bcf = farR ? extb[3 + 1024] : extb[3];
#pragma unroll
    for (int mq = 0; mq < 2; ++mq) {
      const int row = wv * 32 + mq * 16 + lo;  // local q-row
      const float l = il[mq];
#pragma unroll
      for (int mk = 0; mk < 4; ++mk) {
        const int c0 = mk * 16 + hi * 4;  // local k-col base (4-aligned)
        float p4[4];
        if (farT) {
#pragma unroll
          for (int i = 0; i < 4; ++i)
            p4[i] = exp2f_fast(fmaf(sacc[mk][mq][i], C_SC, bcf)) * l;
        } else {
          int k0 = (t * 64 + c0) - (q0 + row) + 515;
          k0 = k0 < 0 ? 0 : (k0 > 1030 ? 1030 : k0);
#pragma unroll
          for (int i = 0; i < 4; ++i)
            p4[i] = exp2f_fast(fmaf(sacc[mk][mq][i], C_SC, extb[k0 + i])) * l;
        }
        ushort4 u = make_ushort4(f2bf(p4[0]), f2bf(p4[1]), f2bf(p4[2]), f2bf(p4[3]));
        *(ushort4*)&lsp[row * 64 + (((c0 >> 3) ^ (row & 7)) << 3) + (c0 & 7)] = u;
        *(float4*)&attnb[(size_t)(q0 + row) * 2048 + t * 64 + c0] =
            make_float4(p4[0], p4[1], p4[2], p4[3]);
      }
    }
    WAITLGKM();
    BAR();
    __builtin_amdgcn_s_setprio(1);
#pragma unroll
    for (int kk = 0; kk < 2; ++kk) {
      const int g = kk * 4 + hi;
      bf16x8 ap[2], bv2[4];
#pragma unroll
      for (int m = 0; m < 2; ++m) {
        int r = wv * 32 + m * 16 + lo;
        ap[m] = *(const bf16x8*)&lsp[r * 64 + ((g ^ (r & 7)) * 8)];
      }
#pragma unroll
      for (int n = 0; n < 4; ++n) {
        int r = n * 16 + lo;
        bv2[n] = *(const bf16x8*)&lsv[t & 1][r * 64 + ((g ^ (r & 7)) * 8)];
      }
#pragma unroll
      for (int m = 0; m < 2; ++m)
#pragma unroll
        for (int n = 0; n < 4; ++n)
          acc_o[m][n] = __builtin_amdgcn_mfma_f32_16x16x32_bf16(ap[m], bv2[n], acc_o[m][n], 0, 0, 0);
    }
    __builtin_amdgcn_s_setprio(0);
  }

  // epilogue: partial O (bf16) -> opart[hf]
  ushort* ob = opart + (size_t)hf * 4194304;
#pragma unroll
  for (int m = 0; m < 2; ++m)
#pragma unroll
    for (int n = 0; n < 4; ++n) {
      int col = h * 64 + n * 16 + lo;
#pragma unroll
      for (int i = 0; i < 4; ++i) {
        int row = q0 + wv * 32 + m * 16 + (hi << 2) + i;
        ob[(size_t)(b * 2048 + row) * 1024 + col] = f2bf(acc_o[m][n][i]);
      }
    }
}

// ctx = bf16(O0 + O1)  (bf16 partials)
__global__ __launch_bounds__(256) void ocomb(const ushort* __restrict__ opart,
                                             ushort* __restrict__ ctx) {
  size_t i = ((size_t)blockIdx.x * 256 + threadIdx.x) * 4;
  ushort4 a = *(const ushort4*)&opart[i];
  ushort4 c = *(const ushort4*)&opart[4194304 + i];
  ushort4 u = make_ushort4(f2bf(bf2f(a.x) + bf2f(c.x)), f2bf(bf2f(a.y) + bf2f(c.y)),
                           f2bf(bf2f(a.z) + bf2f(c.z)), f2bf(bf2f(a.w) + bf2f(c.w)));
  *(ushort4*)&ctx[i] = u;
}

// ---------------- residual(s) + bias + layernorm ----------------
// x = base(f32 af or bf16 ab) + r0 + r1? + bias? ; y = LN(x)*g+be

__global__ __launch_bounds__(256)
void add_ln(const float* __restrict__ af, const ushort* __restrict__ ab,
            const float* __restrict__ r0, const float* __restrict__ r1,
            const float* __restrict__ bias,
            const float* __restrict__ g, const float* __restrict__ be,
            float* __restrict__ outf, ushort* __restrict__ outb) {
  const int tid = threadIdx.x;
  const size_t base = (size_t)blockIdx.x * 1024 + tid * 4;
  float x0, x1, x2, x3;
  if (af) {
    float4 va = *(const float4*)&af[base];
    x0 = va.x; x1 = va.y; x2 = va.z; x3 = va.w;
  } else {
    ushort4 ua = *(const ushort4*)&ab[base];
    x0 = bf2f(ua.x); x1 = bf2f(ua.y); x2 = bf2f(ua.z); x3 = bf2f(ua.w);
  }
  {
    float4 vr = *(const float4*)&r0[base];
    x0 += vr.x; x1 += vr.y; x2 += vr.z; x3 += vr.w;
  }
  if (r1) {
    float4 v1 = *(const float4*)&r1[base];
    x0 += v1.x; x1 += v1.y; x2 += v1.z; x3 += v1.w;
  }
  if (bias) {
    float4 vb4 = *(const float4*)&bias[tid * 4];
    x0 += vb4.x; x1 += vb4.y; x2 += vb4.z; x3 += vb4.w;
  }
  float s = x0 + x1 + x2 + x3;
  float s2 = x0 * x0 + x1 * x1 + x2 * x2 + x3 * x3;
  s = wred_sum(s);
  s2 = wred_sum(s2);
  __shared__ float rs[4], rq[4];
  if ((tid & 63) == 0) { rs[tid >> 6] = s; rq[tid >> 6] = s2; }
  __syncthreads();
  s = rs[0] + rs[1] + rs[2] + rs[3];
  s2 = rq[0] + rq[1] + rq[2] + rq[3];
  const float mean = s * (1.0f / 1024.0f);
  const float var = s2 * (1.0f / 1024.0f) - mean * mean;
  const float sc = rsqrtf(var + 1e-5f);
  float4 vg = *(const float4*)&g[tid * 4];
  float4 vb = *(const float4*)&be[tid * 4];
  float y0 = (x0 - mean) * sc * vg.x + vb.x;
  float y1 = (x1 - mean) * sc * vg.y + vb.y;
  float y2 = (x2 - mean) * sc * vg.z + vb.z;
  float y3 = (x3 - mean) * sc * vg.w + vb.w;
  if (outf) *(float4*)&outf[base] = make_float4(y0, y1, y2, y3);
  if (outb) {
    ushort4 u = make_ushort4(f2bf(y0), f2bf(y1), f2bf(y2), f2bf(y3));
    *(ushort4*)&outb[base] = u;
  }
}

// ---------------- launch ----------------

extern "C" void kernel_launch(void* const* d_in, const int* in_sizes, int n_in,
                              void* d_out, int out_size, void* d_ws, size_t ws_size,
                              hipStream_t stream) {
  const float* x     = (const float*)d_in[0];
  const float* w_qkv = (const float*)d_in[1];
  const float* b_qkv = (const float*)d_in[2];
  const float* w_out = (const float*)d_in[3];
  const float* b_out = (const float*)d_in[4];
  const float* relb  = (const float*)d_in[5];
  const float* g1    = (const float*)d_in[6];
  const float* be1   = (const float*)d_in[7];
  const float* w1    = (const float*)d_in[8];
  const float* b1    = (const float*)d_in[9];
  const float* w2    = (const float*)d_in[10];
  const float* b2    = (const float*)d_in[11];
  const float* g2    = (const float*)d_in[12];
  const float* be2   = (const float*)d_in[13];

  float* x3o  = (float*)d_out;
  float* attn = x3o + (size_t)4194304;

  char* w = (char*)d_ws;
  size_t off = 0;
  auto alloc = [&](size_t bytes) {
    void* p = w + off;
    off += (bytes + 255) & ~(size_t)255;
    return p;
  };
  ushort* x_bf   = (ushort*)alloc(4096ull * 1024 * 2);
  ushort* wqkvT  = (ushort*)alloc(3072ull * 1024 * 2);
  ushort* woutT  = (ushort*)alloc(1024ull * 1024 * 2);
  ushort* w1T    = (ushort*)alloc(4096ull * 1024 * 2);
  ushort* w2T    = (ushort*)alloc(1024ull * 4096 * 2);
  ushort* qkv_bf = (ushort*)alloc(4096ull * 3072 * 2);
  ushort* vT     = (ushort*)alloc(32ull * 64 * 2048 * 2);
  ushort* ctx_bf = (ushort*)alloc(4096ull * 1024 * 2);
  float*  lsum   = (float*)alloc(2ull * 32 * 2048 * 4);
  ushort* opart  = (ushort*)alloc(2ull * 4096 * 1024 * 2);
  float*  p0     = (float*)alloc(4096ull * 1024 * 4);
  float*  p1     = (float*)alloc(4096ull * 1024 * 4);
  ushort* x2bf   = (ushort*)alloc(4096ull * 1024 * 2);
  ushort* ff1_bf = (ushort*)alloc(4096ull * 4096 * 2);

  prep<<<16384, 256, 0, stream>>>(x, x_bf, w_qkv, wqkvT, w1, w1T, w2, w2T,
                                  w_out, woutT);
  gemm128<false, false, true><<<dim3(24, 32), 256, 0, stream>>>(
      x_bf, 1024, wqkvT, 1024, b_qkv, nullptr, qkv_bf, 3072, 1024, 0);
  attn_den_vt<<<2048, 256, 0, stream>>>(qkv_bf, relb, lsum, vT);
  attn_pv2<<<1024, 256, 0, stream>>>(qkv_bf, vT, relb, lsum, attn, opart);
  ocomb<<<4096, 256, 0, stream>>>(opart, ctx_bf);

  // out-proj: split-K x2 (K=1024 -> 2x512), partials p0/p1; bias folded into LN1
  gemm128<false, true, false><<<dim3(8, 32, 2), 256, 0, stream>>>(
      ctx_bf, 1024, woutT, 1024, nullptr, p0, nullptr, 1024, 512,
      (size_t)(p1 - p0));
  // LN1: x2 = LN(x + p0 + p1 + b_out); bf16 out only (LN2 reuses x2bf)
  add_ln<<<4096, 256, 0, stream>>>(x, nullptr, p0, p1, b_out,
                                   g1, be1, nullptr, x2bf);
  gemm128<true, false, true><<<dim3(32, 32), 256, 0, stream>>>(
      x2bf, 1024, w1T, 1024, b1, nullptr, ff1_bf, 4096, 1024, 0);
  // ff2: split-K x2 (K=4096 -> 2x2048); bias folded into LN2
  gemm128<false, true, false><<<dim3(8, 32, 2), 256, 0, stream>>>(
      ff1_bf, 4096, w2T, 4096, nullptr, p0, nullptr, 1024, 2048,
      (size_t)(p1 - p0));
  add_ln<<<4096, 256, 0, stream>>>(nullptr, x2bf, p0, p1, b2,
                                   g2, be2, x3o, nullptr);
}